// Round 4
// baseline (235.289 us; speedup 1.0000x reference)
//
#include <hip/hip_runtime.h>
#include <math.h>

// Problem constants (match reference setup_inputs)
#define BB 64       // batch
#define KK 4        // classes
#define CC 256      // feature dim
#define NN 8192     // bank entries per class
#define NROWS (KK*NN)        // 32768 bank rows
#define GRID_INTER 512       // WGs
#define WPG 4                // waves per WG (256 threads)
#define TILES (GRID_INTER*WPG)   // 2048 tiles x 16 rows = 32768 rows

// d_ws byte offsets
#define WS_B_OFF     0        // 32768 B : bf16 anchor B-fragments (frag order)
#define WS_SLOT_OFF  32768    // 8192 B  : double slots[512][2] (ep,en per WG)
#define WS_NLL_OFF   40960    // 256 B   : float nll[64]
#define WS_INTRA_OFF 41216    // 256 B   : float intra[64]
#define WS_TKT_OFF   41472    // 4 B     : unsigned ticket

#define EPS_NLL 1e-7f

typedef __attribute__((ext_vector_type(8))) short bf16x8;  // MFMA A/B frag
typedef __attribute__((ext_vector_type(4))) float f32x4;   // MFMA C/D frag

__device__ __forceinline__ float4 f4add(float4 a, float4 b){ return make_float4(a.x+b.x, a.y+b.y, a.z+b.z, a.w+b.w); }
__device__ __forceinline__ float4 f4scale(float4 a, float s){ return make_float4(a.x*s, a.y*s, a.z*s, a.w*s); }
__device__ __forceinline__ float dot4(float4 a, float4 b){ return a.x*b.x + a.y*b.y + a.z*b.z + a.w*b.w; }

__device__ __forceinline__ float wred(float v){
#pragma unroll
  for (int m = 32; m >= 1; m >>= 1) v += __shfl_xor(v, m, 64);
  return v;
}

// fp32 -> bf16 round-to-nearest-even (bit trick; no NaN inputs here)
__device__ __forceinline__ unsigned short f2bf(float x){
  union { float f; unsigned u; } v; v.f = x;
  unsigned r = v.u + 0x7fffu + ((v.u >> 16) & 1u);
  return (unsigned short)(r >> 16);
}

// ---------------------------------------------------------------------------
// prep: per-b (64 blocks, 1 wave each)
//  - anchors -> bf16, stored in MFMA B-fragment lane order:
//    frag (kc,nt): lane l, elem j  <->  B[k=kc*32+(l>>4)*8+j][n=nt*16+(l&15)]
//  - intra-modality loss term per b ; NLL surv term per b
// ---------------------------------------------------------------------------
__global__ __launch_bounds__(64) void prep_kernel(
    const float* __restrict__ hazards, const float* __restrict__ S,
    const float* __restrict__ indiv,   const float* __restrict__ gene,
    const float* __restrict__ path,    const int* __restrict__ label,
    const int* __restrict__ cvec,      char* __restrict__ ws)
{
  const int b = blockIdx.x;
  const int lane = threadIdx.x;          // 0..63, owns k = 4*lane .. 4*lane+3

  const float4* ind4 = (const float4*)indiv + (size_t)b * 256;  // [4][64] float4
  float4 i0 = ind4[  0 + lane];
  float4 i1 = ind4[ 64 + lane];
  float4 i2 = ind4[128 + lane];
  float4 i3 = ind4[192 + lane];
  float4 g  = ((const float4*)gene)[b*64 + lane];
  float4 p  = ((const float4*)path)[b*64 + lane];

  // anchor = l2norm(mean over the 4 components)
  float4 am = f4scale(f4add(f4add(i0, i1), f4add(i2, i3)), 0.25f);
  float na = sqrtf(wred(dot4(am, am)));
  float4 an = f4scale(am, 1.0f / fmaxf(na, 1e-12f));

  // write bf16 B-fragment: this lane covers k = 4*cq..4*cq+3 of anchor b
  {
    const int cq = lane;
    const unsigned addr = (unsigned)((cq >> 3) * 4096          // kc
                        + (b >> 4) * 1024                      // nt
                        + ((((cq >> 1) & 3) * 16) + (b & 15)) * 16  // frag lane
                        + (cq & 1) * 8);                       // half (j>>2)
    ushort4 h4;
    h4.x = f2bf(an.x); h4.y = f2bf(an.y); h4.z = f2bf(an.z); h4.w = f2bf(an.w);
    *(ushort4*)(ws + WS_B_OFF + addr) = h4;
  }

  // l2norm the 6 vectors (4 indiv comps, gene, path)
  float4 v[6] = {i0, i1, i2, i3, g, p};
#pragma unroll
  for (int j = 0; j < 6; ++j) {
    float n = sqrtf(wred(dot4(v[j], v[j])));
    v[j] = f4scale(v[j], 1.0f / fmaxf(n, 1e-12f));
  }

  // sims[p][t] = indiv_n[p] . gp_n[t]
  float s[4][2];
#pragma unroll
  for (int pp = 0; pp < 4; ++pp)
#pragma unroll
    for (int t = 0; t < 2; ++t)
      s[pp][t] = wred(dot4(v[pp], v[4+t]));

  if (lane == 0) {
    // MASK rows (common, synergy, g_spec, p_spec) x (gene, path):
    // [[1,1],[0,0],[1,0],[0,1]]; term = |s|*(1-m) - m*s
    float intra = (-s[0][0]) + (-s[0][1])
                + fabsf(s[1][0]) + fabsf(s[1][1])
                + (-s[2][0]) + fabsf(s[2][1])
                + fabsf(s[3][0]) + (-s[3][1]);
    intra = intra * 0.125f + 1.0f;
    ((float*)(ws + WS_INTRA_OFF))[b] = intra;

    // NLL surv (ALPHA = 0)
    int   Y  = label[b];
    float cf = (float)cvec[b];
    float s_y  = (Y == 0) ? 1.0f : S[b*KK + Y - 1];  // S_padded[Y]
    float s_y1 = S[b*KK + Y];                         // S_padded[Y+1]
    float h_y  = hazards[b*KK + Y];
    float neg_l = -cf * logf(fmaxf(s_y1, EPS_NLL))
                  - (1.0f - cf) * (logf(fmaxf(s_y, EPS_NLL)) + logf(fmaxf(h_y, EPS_NLL)));
    ((float*)(ws + WS_NLL_OFF))[b] = neg_l;
  }
}

// ---------------------------------------------------------------------------
// inter v4 (MFMA): each wave owns one 16-row tile.
//  - loads the tile's 4 components straight from global in fragment order
//    (lane l -> row l&15, k-group l>>4), sums comps in registers
//  - row l2norm via 2x shfl_xor (groups share l&15)
//  - bf16 A-frags  x  LDS-staged B-frags -> 8x4 mfma_f32_16x16x32_bf16
//  - D layout (verified): col n = lane&15 (anchor), row m = (lane>>4)*4+reg
// ---------------------------------------------------------------------------
__global__ __launch_bounds__(256) void inter_kernel(
    const float* __restrict__ bank, const int* __restrict__ label,
    char* __restrict__ ws, float* __restrict__ out)
{
  __shared__ uint4 Bl[2048];                // 32 KB: 32 frags x 64 lanes x 16B
  __shared__ double redw[WPG][2];
  __shared__ unsigned tkt_s;

  const int tid  = threadIdx.x;
  const int wave = tid >> 6;
  const int lane = tid & 63;
  const int lm   = lane & 15;               // row-in-tile / anchor-in-ntile
  const int lg   = lane >> 4;               // k-group

  // stage B-fragments into LDS (tid-contiguous uint4 loads)
  const uint4* Bg = (const uint4*)(ws + WS_B_OFF);
#pragma unroll
  for (int i = 0; i < 8; ++i) Bl[tid + i*256] = Bg[tid + i*256];
  __syncthreads();

  const int gw   = blockIdx.x * WPG + wave;  // tile id, 0..2047
  const int row0 = gw * 16;
  const int kk   = row0 >> 13;               // class of the whole tile (16|8192)

  int lab[4];
#pragma unroll
  for (int nt = 0; nt < 4; ++nt) lab[nt] = label[nt*16 + lm];

  // ---- load 4 components at fragment-ordered offsets, sum into sA ----
  const float* rp = bank + (size_t)(row0 + lm) * 1024 + lg * 8;  // f32 units

  float4 sA[8][2];
#pragma unroll
  for (int kc = 0; kc < 8; ++kc)
#pragma unroll
    for (int p = 0; p < 2; ++p)
      sA[kc][p] = *(const float4*)(rp + kc*32 + p*4);
#pragma unroll
  for (int c = 1; c < 4; ++c)
#pragma unroll
    for (int kc = 0; kc < 8; ++kc)
#pragma unroll
      for (int p = 0; p < 2; ++p) {
        float4 t = *(const float4*)(rp + c*256 + kc*32 + p*4);
        sA[kc][p] = f4add(sA[kc][p], t);
      }

  // ---- row norm: this lane's partial, then sum across the 4 k-groups ----
  // normalized = mean/||mean|| = sum/||sum||  (the /4 cancels)
  float ss = 0.0f;
#pragma unroll
  for (int kc = 0; kc < 8; ++kc)
#pragma unroll
    for (int p = 0; p < 2; ++p)
      ss += dot4(sA[kc][p], sA[kc][p]);
  ss += __shfl_xor(ss, 16, 64);
  ss += __shfl_xor(ss, 32, 64);
  const float rs = rsqrtf(fmaxf(ss, 1e-24f));

  // ---- A-frags (bf16) x B-frags (LDS) -> MFMA ----
  f32x4 acc0 = {0,0,0,0}, acc1 = {0,0,0,0}, acc2 = {0,0,0,0}, acc3 = {0,0,0,0};
#pragma unroll
  for (int kc = 0; kc < 8; ++kc) {
    float4 u = sA[kc][0], v = sA[kc][1];
    bf16x8 a;
    a[0] = (short)f2bf(u.x*rs); a[1] = (short)f2bf(u.y*rs);
    a[2] = (short)f2bf(u.z*rs); a[3] = (short)f2bf(u.w*rs);
    a[4] = (short)f2bf(v.x*rs); a[5] = (short)f2bf(v.y*rs);
    a[6] = (short)f2bf(v.z*rs); a[7] = (short)f2bf(v.w*rs);
    acc0 = __builtin_amdgcn_mfma_f32_16x16x32_bf16(a, *(const bf16x8*)&Bl[(kc*4+0)*64 + lane], acc0, 0, 0, 0);
    acc1 = __builtin_amdgcn_mfma_f32_16x16x32_bf16(a, *(const bf16x8*)&Bl[(kc*4+1)*64 + lane], acc1, 0, 0, 0);
    acc2 = __builtin_amdgcn_mfma_f32_16x16x32_bf16(a, *(const bf16x8*)&Bl[(kc*4+2)*64 + lane], acc2, 0, 0, 0);
    acc3 = __builtin_amdgcn_mfma_f32_16x16x32_bf16(a, *(const bf16x8*)&Bl[(kc*4+3)*64 + lane], acc3, 0, 0, 0);
  }

  // ---- exp(sim/TAU), classify by anchor label vs tile class ----
  float epf = 0.0f, enf = 0.0f;
#define DO_NT(ACC, NT)                                                        \
  {                                                                           \
    float es = expf(ACC.x * 0.5f) + expf(ACC.y * 0.5f)                        \
             + expf(ACC.z * 0.5f) + expf(ACC.w * 0.5f);                       \
    if (lab[NT] == kk) epf += es; else enf += es;                             \
  }
  DO_NT(acc0, 0) DO_NT(acc1, 1) DO_NT(acc2, 2) DO_NT(acc3, 3)
#undef DO_NT

  epf = wred(epf);
  enf = wred(enf);
  if (lane == 0) {
    redw[wave][0] = (double)epf;
    redw[wave][1] = (double)enf;
  }
  __syncthreads();

  double*   slots  = (double*)(ws + WS_SLOT_OFF);
  unsigned* ticket = (unsigned*)(ws + WS_TKT_OFF);

  if (tid == 0) {
    double bep = 0.0, ben = 0.0;
#pragma unroll
    for (int w = 0; w < WPG; ++w) { bep += redw[w][0]; ben += redw[w][1]; }
    slots[blockIdx.x*2 + 0] = bep;
    slots[blockIdx.x*2 + 1] = ben;
    __threadfence();
    tkt_s = atomicAdd(ticket, 1u);
  }
  __syncthreads();

  if (tkt_s == GRID_INTER - 1 && wave == 0) {   // last WG finalizes
    __threadfence();
    double pep = 0.0, pen = 0.0;
    for (int i = lane; i < GRID_INTER; i += 64) {
      pep += slots[2*i + 0];
      pen += slots[2*i + 1];
    }
#pragma unroll
    for (int m = 32; m >= 1; m >>= 1) {
      pep += __shfl_xor(pep, m, 64);
      pen += __shfl_xor(pen, m, 64);
    }
    float scal = ((const float*)(ws + WS_NLL_OFF))[lane]
               + ((const float*)(ws + WS_INTRA_OFF))[lane];
    scal = wred(scal);
    if (lane == 0) {
      double ep = pep / (double)(BB * NN);              // mean over positives
      double en = pen / (double)(BB * (KK-1) * NN);     // mean over negatives
      double inter = -log((ep + 1e-8) / (ep + en + 1e-8));
      out[0] = (float)((double)scal / 64.0 + inter);
    }
  }
}

extern "C" void kernel_launch(void* const* d_in, const int* in_sizes, int n_in,
                              void* d_out, int out_size, void* d_ws, size_t ws_size,
                              hipStream_t stream)
{
  const float* hazards = (const float*)d_in[0];
  const float* S       = (const float*)d_in[1];
  const float* indiv   = (const float*)d_in[2];
  const float* gene    = (const float*)d_in[3];
  const float* path    = (const float*)d_in[4];
  const float* bank    = (const float*)d_in[5];
  const int*   label   = (const int*)d_in[6];
  const int*   cvec    = (const int*)d_in[7];
  char*  ws  = (char*)d_ws;
  float* out = (float*)d_out;

  hipMemsetAsync(ws + WS_TKT_OFF, 0, 4, stream);  // zero the ticket only
  prep_kernel<<<dim3(BB), dim3(64), 0, stream>>>(hazards, S, indiv, gene, path, label, cvec, ws);
  inter_kernel<<<dim3(GRID_INTER), dim3(256), 0, stream>>>(bank, label, ws, out);
}

// Round 5
// 229.712 us; speedup vs baseline: 1.0243x; 1.0243x over previous
//
#include <hip/hip_runtime.h>
#include <math.h>

// Problem constants (match reference setup_inputs)
#define BB 64       // batch
#define KK 4        // classes
#define CC 256      // feature dim
#define NN 8192     // bank entries per class
#define NROWS (KK*NN)        // 32768 bank rows
#define GRID_NORM 2048       // bank_norm WGs (256 thr, 4 waves, 4 rows/wave)
#define GRID_INTER 512       // inter WGs
#define WPG 4                // waves per WG (256 threads)

// d_ws byte offsets (ws is ~512 MB; we use ~16.8 MB)
#define WS_BN_OFF    0           // 16777216 B : bf16 normalized rows [32768][256]
#define WS_B_OFF     16777216    // 32768 B : bf16 anchor B-fragments (frag order)
#define WS_SLOT_OFF  16809984    // 8192 B  : double slots[512][2]
#define WS_NLL_OFF   16818176    // 256 B   : float nll[64]
#define WS_INTRA_OFF 16818432    // 256 B   : float intra[64]
#define WS_TKT_OFF   16818688    // 4 B     : unsigned ticket

#define EPS_NLL 1e-7f

typedef __attribute__((ext_vector_type(8))) short bf16x8;  // MFMA A/B frag
typedef __attribute__((ext_vector_type(4))) float f32x4;   // MFMA C/D frag

__device__ __forceinline__ float4 f4add(float4 a, float4 b){ return make_float4(a.x+b.x, a.y+b.y, a.z+b.z, a.w+b.w); }
__device__ __forceinline__ float4 f4scale(float4 a, float s){ return make_float4(a.x*s, a.y*s, a.z*s, a.w*s); }
__device__ __forceinline__ float dot4(float4 a, float4 b){ return a.x*b.x + a.y*b.y + a.z*b.z + a.w*b.w; }

__device__ __forceinline__ float wred(float v){
#pragma unroll
  for (int m = 32; m >= 1; m >>= 1) v += __shfl_xor(v, m, 64);
  return v;
}

// fp32 -> bf16 round-to-nearest-even (bit trick; no NaN inputs here)
__device__ __forceinline__ unsigned short f2bf(float x){
  union { float f; unsigned u; } v; v.f = x;
  unsigned r = v.u + 0x7fffu + ((v.u >> 16) & 1u);
  return (unsigned short)(r >> 16);
}

// ---------------------------------------------------------------------------
// prep: per-b (64 blocks, 1 wave each)
//  - anchors -> bf16, stored in MFMA B-fragment lane order (verified r4)
//  - intra-modality loss term per b ; NLL surv term per b
// ---------------------------------------------------------------------------
__global__ __launch_bounds__(64) void prep_kernel(
    const float* __restrict__ hazards, const float* __restrict__ S,
    const float* __restrict__ indiv,   const float* __restrict__ gene,
    const float* __restrict__ path,    const int* __restrict__ label,
    const int* __restrict__ cvec,      char* __restrict__ ws)
{
  const int b = blockIdx.x;
  const int lane = threadIdx.x;          // 0..63, owns k = 4*lane .. 4*lane+3

  const float4* ind4 = (const float4*)indiv + (size_t)b * 256;  // [4][64] float4
  float4 i0 = ind4[  0 + lane];
  float4 i1 = ind4[ 64 + lane];
  float4 i2 = ind4[128 + lane];
  float4 i3 = ind4[192 + lane];
  float4 g  = ((const float4*)gene)[b*64 + lane];
  float4 p  = ((const float4*)path)[b*64 + lane];

  // anchor = l2norm(mean over the 4 components)
  float4 am = f4scale(f4add(f4add(i0, i1), f4add(i2, i3)), 0.25f);
  float na = sqrtf(wred(dot4(am, am)));
  float4 an = f4scale(am, 1.0f / fmaxf(na, 1e-12f));

  // write bf16 B-fragment: this lane covers k = 4*cq..4*cq+3 of anchor b
  {
    const int cq = lane;
    const unsigned addr = (unsigned)((cq >> 3) * 4096          // kc
                        + (b >> 4) * 1024                      // nt
                        + ((((cq >> 1) & 3) * 16) + (b & 15)) * 16  // frag lane
                        + (cq & 1) * 8);                       // half (j>>2)
    ushort4 h4;
    h4.x = f2bf(an.x); h4.y = f2bf(an.y); h4.z = f2bf(an.z); h4.w = f2bf(an.w);
    *(ushort4*)(ws + WS_B_OFF + addr) = h4;
  }

  // l2norm the 6 vectors (4 indiv comps, gene, path)
  float4 v[6] = {i0, i1, i2, i3, g, p};
#pragma unroll
  for (int j = 0; j < 6; ++j) {
    float n = sqrtf(wred(dot4(v[j], v[j])));
    v[j] = f4scale(v[j], 1.0f / fmaxf(n, 1e-12f));
  }

  // sims[p][t] = indiv_n[p] . gp_n[t]
  float s[4][2];
#pragma unroll
  for (int pp = 0; pp < 4; ++pp)
#pragma unroll
    for (int t = 0; t < 2; ++t)
      s[pp][t] = wred(dot4(v[pp], v[4+t]));

  if (lane == 0) {
    // MASK rows (common, synergy, g_spec, p_spec) x (gene, path):
    // [[1,1],[0,0],[1,0],[0,1]]; term = |s|*(1-m) - m*s
    float intra = (-s[0][0]) + (-s[0][1])
                + fabsf(s[1][0]) + fabsf(s[1][1])
                + (-s[2][0]) + fabsf(s[2][1])
                + fabsf(s[3][0]) + (-s[3][1]);
    intra = intra * 0.125f + 1.0f;
    ((float*)(ws + WS_INTRA_OFF))[b] = intra;

    // NLL surv (ALPHA = 0)
    int   Y  = label[b];
    float cf = (float)cvec[b];
    float s_y  = (Y == 0) ? 1.0f : S[b*KK + Y - 1];  // S_padded[Y]
    float s_y1 = S[b*KK + Y];                         // S_padded[Y+1]
    float h_y  = hazards[b*KK + Y];
    float neg_l = -cf * logf(fmaxf(s_y1, EPS_NLL))
                  - (1.0f - cf) * (logf(fmaxf(s_y, EPS_NLL)) + logf(fmaxf(h_y, EPS_NLL)));
    ((float*)(ws + WS_NLL_OFF))[b] = neg_l;
  }
}

// ---------------------------------------------------------------------------
// bank_norm: pure streaming pass. 2048 WGs x 4 waves; each wave owns 4
// contiguous bank entries (4 x 4KB). Per row: 4 coalesced 1KB loads (one per
// component), register sum, rsqrt norm (sum/||sum|| == mean/||mean||),
// bf16 convert, coalesced 512B store. 16 independent loads per wave.
// ---------------------------------------------------------------------------
__global__ __launch_bounds__(256, 4) void bank_norm_kernel(
    const float* __restrict__ bank, char* __restrict__ ws)
{
  const int tid  = threadIdx.x;
  const int wave = tid >> 6;
  const int lane = tid & 63;
  const int gw   = blockIdx.x * WPG + wave;   // 0..8191
  const int row0 = gw * 4;

  const float4* b4 = (const float4*)bank;     // entry stride 256 float4
  ushort4* bn = (ushort4*)(ws + WS_BN_OFF);   // row stride 64 ushort4

  // load 4 rows x 4 comps, all independent
  float4 r[4][4];
#pragma unroll
  for (int rr = 0; rr < 4; ++rr)
#pragma unroll
    for (int c = 0; c < 4; ++c)
      r[rr][c] = b4[(size_t)(row0 + rr) * 256 + c * 64 + lane];

#pragma unroll
  for (int rr = 0; rr < 4; ++rr) {
    float4 m = f4add(f4add(r[rr][0], r[rr][1]), f4add(r[rr][2], r[rr][3]));
    float ss = wred(dot4(m, m));
    float rs = rsqrtf(fmaxf(ss, 1e-24f));
    ushort4 h4;
    h4.x = f2bf(m.x * rs); h4.y = f2bf(m.y * rs);
    h4.z = f2bf(m.z * rs); h4.w = f2bf(m.w * rs);
    bn[(size_t)(row0 + rr) * 64 + lane] = h4;
  }
}

// ---------------------------------------------------------------------------
// inter v5: each wave owns one 16-row tile of the PRE-NORMALIZED bf16 rows.
// A-frags: 8 independent dwordx4 global loads (L2/L3-warm, frag-ordered).
// B-frags staged in 32KB LDS. 8x4 mfma_f32_16x16x32_bf16, exp, ticket-reduce.
// D layout (verified r4): col n = lane&15, row m = (lane>>4)*4+reg.
// ---------------------------------------------------------------------------
__global__ __launch_bounds__(256) void inter_kernel(
    const int* __restrict__ label, char* __restrict__ ws, float* __restrict__ out)
{
  __shared__ uint4 Bl[2048];                // 32 KB: 32 frags x 64 lanes x 16B
  __shared__ double redw[WPG][2];
  __shared__ unsigned tkt_s;

  const int tid  = threadIdx.x;
  const int wave = tid >> 6;
  const int lane = tid & 63;
  const int lm   = lane & 15;               // row-in-tile / anchor-in-ntile
  const int lg   = lane >> 4;               // k-group

  // stage B-fragments into LDS (tid-contiguous uint4 loads)
  const uint4* Bg = (const uint4*)(ws + WS_B_OFF);
#pragma unroll
  for (int i = 0; i < 8; ++i) Bl[tid + i*256] = Bg[tid + i*256];
  __syncthreads();

  const int gw   = blockIdx.x * WPG + wave;  // tile id, 0..2047
  const int row0 = gw * 16;
  const int kk   = row0 >> 13;               // class of the whole tile (16|8192)

  int lab[4];
#pragma unroll
  for (int nt = 0; nt < 4; ++nt) lab[nt] = label[nt*16 + lm];

  // ---- A-frags: 8 independent 16B loads from bn rows ----
  // lane l, frag kc: A[row=lm][k = kc*32 + lg*8 + j], j=0..7 (bf16)
  const short* bnp = (const short*)(ws + WS_BN_OFF) + (size_t)(row0 + lm) * 256 + lg * 8;
  bf16x8 af[8];
#pragma unroll
  for (int kc = 0; kc < 8; ++kc)
    af[kc] = *(const bf16x8*)(bnp + kc * 32);

  // ---- MFMA: A-frags x B-frags ----
  f32x4 acc0 = {0,0,0,0}, acc1 = {0,0,0,0}, acc2 = {0,0,0,0}, acc3 = {0,0,0,0};
#pragma unroll
  for (int kc = 0; kc < 8; ++kc) {
    acc0 = __builtin_amdgcn_mfma_f32_16x16x32_bf16(af[kc], *(const bf16x8*)&Bl[(kc*4+0)*64 + lane], acc0, 0, 0, 0);
    acc1 = __builtin_amdgcn_mfma_f32_16x16x32_bf16(af[kc], *(const bf16x8*)&Bl[(kc*4+1)*64 + lane], acc1, 0, 0, 0);
    acc2 = __builtin_amdgcn_mfma_f32_16x16x32_bf16(af[kc], *(const bf16x8*)&Bl[(kc*4+2)*64 + lane], acc2, 0, 0, 0);
    acc3 = __builtin_amdgcn_mfma_f32_16x16x32_bf16(af[kc], *(const bf16x8*)&Bl[(kc*4+3)*64 + lane], acc3, 0, 0, 0);
  }

  // ---- exp(sim/TAU), classify by anchor label vs tile class ----
  float epf = 0.0f, enf = 0.0f;
#define DO_NT(ACC, NT)                                                        \
  {                                                                           \
    float es = expf(ACC.x * 0.5f) + expf(ACC.y * 0.5f)                        \
             + expf(ACC.z * 0.5f) + expf(ACC.w * 0.5f);                       \
    if (lab[NT] == kk) epf += es; else enf += es;                             \
  }
  DO_NT(acc0, 0) DO_NT(acc1, 1) DO_NT(acc2, 2) DO_NT(acc3, 3)
#undef DO_NT

  epf = wred(epf);
  enf = wred(enf);
  if (lane == 0) {
    redw[wave][0] = (double)epf;
    redw[wave][1] = (double)enf;
  }
  __syncthreads();

  double*   slots  = (double*)(ws + WS_SLOT_OFF);
  unsigned* ticket = (unsigned*)(ws + WS_TKT_OFF);

  if (tid == 0) {
    double bep = 0.0, ben = 0.0;
#pragma unroll
    for (int w = 0; w < WPG; ++w) { bep += redw[w][0]; ben += redw[w][1]; }
    slots[blockIdx.x*2 + 0] = bep;
    slots[blockIdx.x*2 + 1] = ben;
    __threadfence();
    tkt_s = atomicAdd(ticket, 1u);
  }
  __syncthreads();

  if (tkt_s == GRID_INTER - 1 && wave == 0) {   // last WG finalizes
    __threadfence();
    double pep = 0.0, pen = 0.0;
    for (int i = lane; i < GRID_INTER; i += 64) {
      pep += slots[2*i + 0];
      pen += slots[2*i + 1];
    }
#pragma unroll
    for (int m = 32; m >= 1; m >>= 1) {
      pep += __shfl_xor(pep, m, 64);
      pen += __shfl_xor(pen, m, 64);
    }
    float scal = ((const float*)(ws + WS_NLL_OFF))[lane]
               + ((const float*)(ws + WS_INTRA_OFF))[lane];
    scal = wred(scal);
    if (lane == 0) {
      double ep = pep / (double)(BB * NN);              // mean over positives
      double en = pen / (double)(BB * (KK-1) * NN);     // mean over negatives
      double inter = -log((ep + 1e-8) / (ep + en + 1e-8));
      out[0] = (float)((double)scal / 64.0 + inter);
    }
  }
}

extern "C" void kernel_launch(void* const* d_in, const int* in_sizes, int n_in,
                              void* d_out, int out_size, void* d_ws, size_t ws_size,
                              hipStream_t stream)
{
  const float* hazards = (const float*)d_in[0];
  const float* S       = (const float*)d_in[1];
  const float* indiv   = (const float*)d_in[2];
  const float* gene    = (const float*)d_in[3];
  const float* path    = (const float*)d_in[4];
  const float* bank    = (const float*)d_in[5];
  const int*   label   = (const int*)d_in[6];
  const int*   cvec    = (const int*)d_in[7];
  char*  ws  = (char*)d_ws;
  float* out = (float*)d_out;

  hipMemsetAsync(ws + WS_TKT_OFF, 0, 4, stream);  // zero the ticket only
  prep_kernel<<<dim3(BB), dim3(64), 0, stream>>>(hazards, S, indiv, gene, path, label, cvec, ws);
  bank_norm_kernel<<<dim3(GRID_NORM), dim3(256), 0, stream>>>(bank, ws);
  inter_kernel<<<dim3(GRID_INTER), dim3(256), 0, stream>>>(label, ws, out);
}